// Round 11
// baseline (436.736 us; speedup 1.0000x reference)
//
#include <hip/hip_runtime.h>
#include <stdint.h>

// PoissonNeuronTransform — bit-exact vs the harness's NUMPY reference (ref=np):
//   bits  = threefry2x32 partitionable: out0^out1 of ctr=(0, flat_idx), key=(0,42)
//           [confirmed round 1: absmax 39 -> 1.0]
//   u     = bitcast((bits>>9)|0x3f800000) - 1.0f                      [exact]
//   expo  = -np.log1p(-u), float32 -> libm log1pf = classic fdlibm
//           s_log1pf.c (glibc baseline build, NO FMA, plain f32 ops)
//   delta = expo / rate + 0.002f          [IEEE f32 div; exact f32 add]
//   cumsum: np.cumsum axis=0 = STRICTLY SEQUENTIAL f32 running sum
//           (not the lax.associative_scan tree — that was the JAX world)
//   out   = #(prefix < 1.0f), int32

static constexpr int kElems  = 256 * 32 * 128;  // 1048576 output elements
static constexpr int kSpikes = 100;             // NUM_SPIKES

__device__ __forceinline__ uint32_t rotl32(uint32_t v, uint32_t d) {
  return (v << d) | (v >> (32u - d));
}

// threefry2x32 with key (0, 42) — matches jax.random.key(42).
__device__ __forceinline__ void threefry2x32_0_42(uint32_t x0, uint32_t x1,
                                                  uint32_t& o0, uint32_t& o1) {
  const uint32_t ks0 = 0u;
  const uint32_t ks1 = 42u;
  const uint32_t ks2 = 0x1BD11BDAu ^ 0u ^ 42u;
  uint32_t a = x0 + ks0;
  uint32_t b = x1 + ks1;
#define TF_ROUND(r) { a += b; b = rotl32(b, (r)); b ^= a; }
  TF_ROUND(13u) TF_ROUND(15u) TF_ROUND(26u) TF_ROUND(6u)
  a += ks1; b += ks2 + 1u;
  TF_ROUND(17u) TF_ROUND(29u) TF_ROUND(16u) TF_ROUND(24u)
  a += ks2; b += ks0 + 2u;
  TF_ROUND(13u) TF_ROUND(15u) TF_ROUND(26u) TF_ROUND(6u)
  a += ks0; b += ks1 + 3u;
  TF_ROUND(17u) TF_ROUND(29u) TF_ROUND(16u) TF_ROUND(24u)
  a += ks1; b += ks2 + 4u;
  TF_ROUND(13u) TF_ROUND(15u) TF_ROUND(26u) TF_ROUND(6u)
  a += ks2; b += ks0 + 5u;
#undef TF_ROUND
  o0 = a; o1 = b;
}

// Faithful port of glibc sysdeps/ieee754/flt-32/s_log1pf.c (fdlibm).
// Baseline SSE2 build semantics: every op a separate f32 mul/add/sub/div,
// NO contraction. Domain used here: x in (-1, 0].
__device__ __forceinline__ float fdlibm_log1pf(float x) {
#pragma clang fp contract(off)
  const float ln2_hi = __uint_as_float(0x3f317180u);  // 6.9313812256e-01
  const float ln2_lo = __uint_as_float(0x3717f7d1u);  // 9.0580006145e-06
  const float Lp1 = __uint_as_float(0x3F2AAAABu);
  const float Lp2 = __uint_as_float(0x3ECCCCCDu);
  const float Lp3 = __uint_as_float(0x3E924925u);
  const float Lp4 = __uint_as_float(0x3E638E29u);
  const float Lp5 = __uint_as_float(0x3E3A3325u);
  const float Lp6 = __uint_as_float(0x3E1CD04Fu);
  const float Lp7 = __uint_as_float(0x3E178897u);

  int32_t hx = (int32_t)__float_as_uint(x);
  int32_t ax = hx & 0x7fffffff;
  int32_t k = 1, hu = 0;
  float f = 0.0f, c = 0.0f, u;

  if (hx < 0x3ed413d7) {                    // always true for x <= 0
    // (ax >= 0x3f800000 cannot happen: |x| < 1)
    if (ax < 0x38000000) {                  // |x| < 2^-15
      if (ax < 0x33800000) return x;        // |x| < 2^-24
      return x - x * x * 0.5f;              // x - ((x*x)*0.5)
    }
    if (hx > 0 || hx <= (int32_t)0xbe95f61f) {  // -0.2929 < x (for x<0)
      k = 0; f = x; hu = 1;
    }
  }
  if (k != 0) {
    // hx < 0x5a000000 always here
    u = 1.0f + x;
    hu = (int32_t)__float_as_uint(u);
    k = (hu >> 23) - 127;
    c = (k > 0) ? 1.0f - (u - x) : x - (u - 1.0f);  // k<=0 in our domain
    c /= u;
    hu &= 0x007fffff;
    if (hu < 0x3504f7) {
      u = __uint_as_float((uint32_t)hu | 0x3f800000u);
    } else {
      k += 1;
      u = __uint_as_float((uint32_t)hu | 0x3f000000u);
      hu = (0x00800000 - hu) >> 2;
    }
    f = u - 1.0f;
  }
  float hfsq = 0.5f * f * f;                // (0.5*f)*f, left-assoc
  if (hu == 0) {                            // |f| < 2^-20
    if (f == 0.0f) {
      if (k == 0) return 0.0f;
      c += (float)k * ln2_lo;
      return (float)k * ln2_hi + c;
    }
    float R = hfsq * (1.0f - 0.6666666666666666f * f);
    if (k == 0) return f - R;
    return (float)k * ln2_hi - ((R - ((float)k * ln2_lo + c)) - f);
  }
  float s = f / (2.0f + f);
  float z = s * s;
  float R = z * (Lp1 + z * (Lp2 + z * (Lp3 + z * (Lp4 +
            z * (Lp5 + z * (Lp6 + z * Lp7))))));
  if (k == 0) return f - (hfsq - s * (hfsq + R));
  return (float)k * ln2_hi -
         ((hfsq - (s * (hfsq + R) + ((float)k * ln2_lo + c))) - f);
}

__global__ void __launch_bounds__(256) poisson_count_kernel(
    const float* __restrict__ rates, int* __restrict__ out) {
#pragma clang fp contract(off)
  int o = blockIdx.x * blockDim.x + threadIdx.x;
  if (o >= kElems) return;
  float rate = rates[o];

  float run = 0.0f;  // np.cumsum: out[0]=d[0]; 0+d[0]==d[0] exactly
  int cnt = 0;
#pragma unroll 1
  for (int s = 0; s < kSpikes; ++s) {
    // flat index into (100, 256, 32, 128); < 2^32 so ctr = (0, j)
    uint32_t j = (uint32_t)s * (uint32_t)kElems + (uint32_t)o;
    uint32_t b1, b2;
    threefry2x32_0_42(0u, j, b1, b2);
    uint32_t bits = b1 ^ b2;  // partitionable 32-bit fold
    float uu = __uint_as_float((bits >> 9) | 0x3f800000u) - 1.0f;  // [0, 1)
    float expo = -fdlibm_log1pf(-uu);
    float delta = expo / rate + 0.002f;   // IEEE div, then +f32(0.002)
    run = run + delta;                    // SEQUENTIAL f32 accumulation
    cnt += (run < 1.0f) ? 1 : 0;
  }
  out[o] = cnt;
}

extern "C" void kernel_launch(void* const* d_in, const int* in_sizes, int n_in,
                              void* d_out, int out_size, void* d_ws, size_t ws_size,
                              hipStream_t stream) {
  const float* rates = (const float*)d_in[0];
  int* out = (int*)d_out;
  (void)in_sizes; (void)n_in; (void)out_size; (void)d_ws; (void)ws_size;
  int blocks = (kElems + 255) / 256;
  poisson_count_kernel<<<blocks, 256, 0, stream>>>(rates, out);
}

// Round 12
// 413.008 us; speedup vs baseline: 1.0575x; 1.0575x over previous
//
#include <hip/hip_runtime.h>
#include <stdint.h>

// PoissonNeuronTransform — bit-exact vs the harness's NUMPY reference (ref=np).
// Validated round 11 (absmax 0.0): threefry2x32 partitionable bits, uniform
// bit-trick, fdlibm log1pf, IEEE f32 div, +0.002f, sequential f32 cumsum.
// Round 12 (perf only, every transform proven bit-exact):
//  * /rate -> (float)((double)expo * (1.0/(double)rate)): CR-double reciprocal
//    multiply == IEEE f32 division for f32 operands (gap-to-midpoint >= 2^-50
//    rel, total err <= 2^-52 rel; exact quotients preserved).
//  * log1pf made fully branchless: unified k==0/k!=0 final formula (bitwise
//    equal; +0/-0 and f==0 corners verified), tiny-|x| via selects.
//  * #pragma unroll 2 for div-chain ILP.

static constexpr int kElems  = 256 * 32 * 128;  // 1048576 = 2^20
static constexpr int kSpikes = 100;             // NUM_SPIKES

__device__ __forceinline__ uint32_t rotl32(uint32_t v, uint32_t d) {
  return (v << d) | (v >> (32u - d));
}

// threefry2x32 with key (0, 42) — matches jax.random.key(42).
__device__ __forceinline__ void threefry2x32_0_42(uint32_t x0, uint32_t x1,
                                                  uint32_t& o0, uint32_t& o1) {
  const uint32_t ks0 = 0u;
  const uint32_t ks1 = 42u;
  const uint32_t ks2 = 0x1BD11BDAu ^ 0u ^ 42u;
  uint32_t a = x0 + ks0;
  uint32_t b = x1 + ks1;
#define TF_ROUND(r) { a += b; b = rotl32(b, (r)); b ^= a; }
  TF_ROUND(13u) TF_ROUND(15u) TF_ROUND(26u) TF_ROUND(6u)
  a += ks1; b += ks2 + 1u;
  TF_ROUND(17u) TF_ROUND(29u) TF_ROUND(16u) TF_ROUND(24u)
  a += ks2; b += ks0 + 2u;
  TF_ROUND(13u) TF_ROUND(15u) TF_ROUND(26u) TF_ROUND(6u)
  a += ks0; b += ks1 + 3u;
  TF_ROUND(17u) TF_ROUND(29u) TF_ROUND(16u) TF_ROUND(24u)
  a += ks1; b += ks2 + 4u;
  TF_ROUND(13u) TF_ROUND(15u) TF_ROUND(26u) TF_ROUND(6u)
  a += ks2; b += ks0 + 5u;
#undef TF_ROUND
  o0 = a; o1 = b;
}

// Branchless fdlibm s_log1pf for x in (-1, 0]. Bitwise identical to the
// glibc baseline (no-FMA) implementation on this domain:
//  * k==0 region (x > -0.2928932) flows through the unified final formula
//    with kf=0, c=+0, f=x — proven bitwise equal to "f - (hfsq - s*(hfsq+R))"
//    (negation of an fsub is exact; +0 addends don't perturb; 0*c = +0).
//  * f==0 (u = 0.5 exactly) flows through the poly with s=hfsq=R=0 and
//    reproduces the hu==0 special case bitwise.
//  * |x| < 2^-15 and |x| < 2^-24 results selected at the end (main-path
//    computation on those lanes is finite garbage, discarded).
__device__ __forceinline__ float fdlibm_log1pf_nb(float x) {
#pragma clang fp contract(off)
  const float ln2_hi = __uint_as_float(0x3f317180u);  // 6.9313812256e-01
  const float ln2_lo = __uint_as_float(0x3717f7d1u);  // 9.0580006145e-06
  const float Lp1 = __uint_as_float(0x3F2AAAABu);
  const float Lp2 = __uint_as_float(0x3ECCCCCDu);
  const float Lp3 = __uint_as_float(0x3E924925u);
  const float Lp4 = __uint_as_float(0x3E638E29u);
  const float Lp5 = __uint_as_float(0x3E3A3325u);
  const float Lp6 = __uint_as_float(0x3E1CD04Fu);
  const float Lp7 = __uint_as_float(0x3E178897u);

  uint32_t hx = __float_as_uint(x);
  uint32_t ax = hx & 0x7fffffffu;

  // ---- k != 0 machinery (valid for every lane; selected below) ----
  float u = 1.0f + x;
  uint32_t hu = __float_as_uint(u);
  int k = (int)(hu >> 23) - 127;          // pre-adjust exponent (k <= 0 here)
  float c = x - (u - 1.0f);               // k>0 branch impossible on domain
  c = c / u;                              // f32 IEEE div
  uint32_t m = hu & 0x007fffffu;
  bool half = (m >= 0x3504f7u);
  int k2 = half ? (k + 1) : k;
  float u2 = __uint_as_float(m | (half ? 0x3f000000u : 0x3f800000u));
  float f2 = u2 - 1.0f;

  // ---- k == 0 region select: x > -0.29289323 (fdlibm: hx <= 0xbe95f61f) ----
  bool cond0 = ((int32_t)hx <= (int32_t)0xbe95f61fu);
  float kf = cond0 ? 0.0f : (float)k2;
  float ff = cond0 ? x : f2;
  float cc = cond0 ? 0.0f : c;

  // ---- shared tail (fdlibm main formula, unified) ----
  float hfsq = (0.5f * ff) * ff;
  float s = ff / (2.0f + ff);             // f32 IEEE div
  float z = s * s;
  float R = z * (Lp1 + z * (Lp2 + z * (Lp3 + z * (Lp4 +
            z * (Lp5 + z * (Lp6 + z * Lp7))))));
  float lowsum = s * (hfsq + R) + (kf * ln2_lo + cc);
  float res = kf * ln2_hi - ((hfsq - lowsum) - ff);

  // ---- tiny-|x| overrides ----
  float tiny2 = x - (x * x) * 0.5f;       // glibc: x - x*x*0.5
  res = (ax < 0x38000000u) ? ((ax < 0x33800000u) ? x : tiny2) : res;
  return res;
}

__global__ void __launch_bounds__(256) poisson_count_kernel(
    const float* __restrict__ rates, int* __restrict__ out) {
#pragma clang fp contract(off)
  int o = blockIdx.x * blockDim.x + threadIdx.x;
  if (o >= kElems) return;
  float rate = rates[o];
  // CR double reciprocal, hoisted: one f64 divide per thread.
  double inv_d = 1.0 / (double)rate;

  float run = 0.0f;
  int cnt = 0;
#pragma unroll 2
  for (int s = 0; s < kSpikes; ++s) {
    uint32_t j = ((uint32_t)s << 20) + (uint32_t)o;  // kElems == 2^20
    uint32_t b1, b2;
    threefry2x32_0_42(0u, j, b1, b2);
    uint32_t bits = b1 ^ b2;
    float uu = __uint_as_float((bits >> 9) | 0x3f800000u) - 1.0f;  // [0, 1)
    float expo = -fdlibm_log1pf_nb(-uu);
    // == expo / rate (IEEE f32), via proven double-reciprocal multiply:
    float q = (float)((double)expo * inv_d);
    float delta = q + 0.002f;
    run = run + delta;                    // sequential f32 cumsum
    cnt += (run < 1.0f) ? 1 : 0;
  }
  out[o] = cnt;
}

extern "C" void kernel_launch(void* const* d_in, const int* in_sizes, int n_in,
                              void* d_out, int out_size, void* d_ws, size_t ws_size,
                              hipStream_t stream) {
  const float* rates = (const float*)d_in[0];
  int* out = (int*)d_out;
  (void)in_sizes; (void)n_in; (void)out_size; (void)d_ws; (void)ws_size;
  int blocks = (kElems + 255) / 256;
  poisson_count_kernel<<<blocks, 256, 0, stream>>>(rates, out);
}

// Round 13
// 153.419 us; speedup vs baseline: 2.8467x; 2.6920x over previous
//
#include <hip/hip_runtime.h>
#include <stdint.h>

// PoissonNeuronTransform — bit-exact vs the harness's NUMPY reference (ref=np).
// Validated (absmax 0.0, R11/R12): threefry2x32 partitionable bits, uniform
// bit-trick, branchless fdlibm log1pf, double-reciprocal division, +0.002f,
// sequential f32 cumsum, count prefixes < 1.0f.
// Round 13 (perf only, bit-exact by monotonicity proof):
//  * EARLY EXIT: delta >= 0.002f > 0 and IEEE-RN fadd is monotone, so once
//    run >= 1.0f no later prefix can be < 1.0f -> cnt is final. Break the
//    wave when __ballot(run < 1.0f) == 0. Skipped draws never affect output.
//    Expected iterations/wave ~30 vs 100.

static constexpr int kElems  = 256 * 32 * 128;  // 1048576 = 2^20
static constexpr int kSpikes = 100;             // NUM_SPIKES

__device__ __forceinline__ uint32_t rotl32(uint32_t v, uint32_t d) {
  return (v << d) | (v >> (32u - d));
}

// threefry2x32 with key (0, 42) — matches jax.random.key(42).
__device__ __forceinline__ void threefry2x32_0_42(uint32_t x0, uint32_t x1,
                                                  uint32_t& o0, uint32_t& o1) {
  const uint32_t ks0 = 0u;
  const uint32_t ks1 = 42u;
  const uint32_t ks2 = 0x1BD11BDAu ^ 0u ^ 42u;
  uint32_t a = x0 + ks0;
  uint32_t b = x1 + ks1;
#define TF_ROUND(r) { a += b; b = rotl32(b, (r)); b ^= a; }
  TF_ROUND(13u) TF_ROUND(15u) TF_ROUND(26u) TF_ROUND(6u)
  a += ks1; b += ks2 + 1u;
  TF_ROUND(17u) TF_ROUND(29u) TF_ROUND(16u) TF_ROUND(24u)
  a += ks2; b += ks0 + 2u;
  TF_ROUND(13u) TF_ROUND(15u) TF_ROUND(26u) TF_ROUND(6u)
  a += ks0; b += ks1 + 3u;
  TF_ROUND(17u) TF_ROUND(29u) TF_ROUND(16u) TF_ROUND(24u)
  a += ks1; b += ks2 + 4u;
  TF_ROUND(13u) TF_ROUND(15u) TF_ROUND(26u) TF_ROUND(6u)
  a += ks2; b += ks0 + 5u;
#undef TF_ROUND
  o0 = a; o1 = b;
}

// Branchless fdlibm s_log1pf for x in (-1, 0] — bit-exact port (see R12).
__device__ __forceinline__ float fdlibm_log1pf_nb(float x) {
#pragma clang fp contract(off)
  const float ln2_hi = __uint_as_float(0x3f317180u);
  const float ln2_lo = __uint_as_float(0x3717f7d1u);
  const float Lp1 = __uint_as_float(0x3F2AAAABu);
  const float Lp2 = __uint_as_float(0x3ECCCCCDu);
  const float Lp3 = __uint_as_float(0x3E924925u);
  const float Lp4 = __uint_as_float(0x3E638E29u);
  const float Lp5 = __uint_as_float(0x3E3A3325u);
  const float Lp6 = __uint_as_float(0x3E1CD04Fu);
  const float Lp7 = __uint_as_float(0x3E178897u);

  uint32_t hx = __float_as_uint(x);
  uint32_t ax = hx & 0x7fffffffu;

  // k != 0 machinery (valid everywhere; selected below)
  float u = 1.0f + x;
  uint32_t hu = __float_as_uint(u);
  int k = (int)(hu >> 23) - 127;
  float c = x - (u - 1.0f);
  c = c / u;                              // f32 IEEE div
  uint32_t m = hu & 0x007fffffu;
  bool half = (m >= 0x3504f7u);
  int k2 = half ? (k + 1) : k;
  float u2 = __uint_as_float(m | (half ? 0x3f000000u : 0x3f800000u));
  float f2 = u2 - 1.0f;

  // k == 0 region: x > -0.29289323 (fdlibm: hx <= 0xbe95f61f)
  bool cond0 = ((int32_t)hx <= (int32_t)0xbe95f61fu);
  float kf = cond0 ? 0.0f : (float)k2;
  float ff = cond0 ? x : f2;
  float cc = cond0 ? 0.0f : c;

  // shared fdlibm tail
  float hfsq = (0.5f * ff) * ff;
  float s = ff / (2.0f + ff);             // f32 IEEE div
  float z = s * s;
  float R = z * (Lp1 + z * (Lp2 + z * (Lp3 + z * (Lp4 +
            z * (Lp5 + z * (Lp6 + z * Lp7))))));
  float lowsum = s * (hfsq + R) + (kf * ln2_lo + cc);
  float res = kf * ln2_hi - ((hfsq - lowsum) - ff);

  // tiny-|x| overrides
  float tiny2 = x - (x * x) * 0.5f;
  res = (ax < 0x38000000u) ? ((ax < 0x33800000u) ? x : tiny2) : res;
  return res;
}

__global__ void __launch_bounds__(256) poisson_count_kernel(
    const float* __restrict__ rates, int* __restrict__ out) {
#pragma clang fp contract(off)
  int o = blockIdx.x * blockDim.x + threadIdx.x;
  if (o >= kElems) return;
  float rate = rates[o];
  // CR double reciprocal, hoisted: one f64 divide per thread.
  double inv_d = 1.0 / (double)rate;

  float run = 0.0f;
  int cnt = 0;
#pragma unroll 1
  for (int s = 0; s < kSpikes; ++s) {
    uint32_t j = ((uint32_t)s << 20) + (uint32_t)o;  // kElems == 2^20
    uint32_t b1, b2;
    threefry2x32_0_42(0u, j, b1, b2);
    uint32_t bits = b1 ^ b2;
    float uu = __uint_as_float((bits >> 9) | 0x3f800000u) - 1.0f;  // [0, 1)
    float expo = -fdlibm_log1pf_nb(-uu);
    // == expo / rate (IEEE f32) via proven double-reciprocal multiply
    float q = (float)((double)expo * inv_d);
    float delta = q + 0.002f;
    run = run + delta;                    // sequential f32 cumsum
    cnt += (run < 1.0f) ? 1 : 0;
    // Early exit: delta > 0 and RN-fadd monotone => once run >= 1.0f the
    // count is final for this lane; break when the whole wave is done.
    if (__ballot(run < 1.0f) == 0ull) break;
  }
  out[o] = cnt;
}

extern "C" void kernel_launch(void* const* d_in, const int* in_sizes, int n_in,
                              void* d_out, int out_size, void* d_ws, size_t ws_size,
                              hipStream_t stream) {
  const float* rates = (const float*)d_in[0];
  int* out = (int*)d_out;
  (void)in_sizes; (void)n_in; (void)out_size; (void)d_ws; (void)ws_size;
  int blocks = (kElems + 255) / 256;
  poisson_count_kernel<<<blocks, 256, 0, stream>>>(rates, out);
}

// Round 14
// 130.813 us; speedup vs baseline: 3.3386x; 1.1728x over previous
//
#include <hip/hip_runtime.h>
#include <stdint.h>

// PoissonNeuronTransform — bit-exact vs the harness's NUMPY reference (ref=np).
// Validated (absmax 0.0, R11-R13): threefry2x32 partitionable bits, uniform
// bit-trick, branchless fdlibm log1pf, double-reciprocal division, +0.002f,
// sequential f32 cumsum, count prefixes < 1.0f, early exit on run >= 1.0f
// (monotone RN-fadd, delta > 0).
// Round 14 (perf only): WAVE-INTERNAL DYNAMIC LOAD BALANCING.
//   Each wave owns 128 contiguous elements; finished lanes refill from the
//   wave's pool via ballot/popc-prefix (no atomics). Removes the wave-max
//   imbalance (per-lane draws mean ~11, wave-max ~29). Element math depends
//   only on the flat index o and rates[o] -> lane assignment is irrelevant,
//   output unchanged bit-for-bit.

static constexpr int      kElems  = 256 * 32 * 128;   // 1048576 = 2^20
static constexpr int      kSpikes = 100;              // NUM_SPIKES
static constexpr int      kBlocks = 2048;             // x256 thr = 8192 waves
static constexpr uint32_t kEPW    = (uint32_t)kElems / (kBlocks * 4);  // 128

__device__ __forceinline__ uint32_t rotl32(uint32_t v, uint32_t d) {
  return (v << d) | (v >> (32u - d));
}

// threefry2x32 with key (0, 42) — matches jax.random.key(42).
__device__ __forceinline__ void threefry2x32_0_42(uint32_t x0, uint32_t x1,
                                                  uint32_t& o0, uint32_t& o1) {
  const uint32_t ks0 = 0u;
  const uint32_t ks1 = 42u;
  const uint32_t ks2 = 0x1BD11BDAu ^ 0u ^ 42u;
  uint32_t a = x0 + ks0;
  uint32_t b = x1 + ks1;
#define TF_ROUND(r) { a += b; b = rotl32(b, (r)); b ^= a; }
  TF_ROUND(13u) TF_ROUND(15u) TF_ROUND(26u) TF_ROUND(6u)
  a += ks1; b += ks2 + 1u;
  TF_ROUND(17u) TF_ROUND(29u) TF_ROUND(16u) TF_ROUND(24u)
  a += ks2; b += ks0 + 2u;
  TF_ROUND(13u) TF_ROUND(15u) TF_ROUND(26u) TF_ROUND(6u)
  a += ks0; b += ks1 + 3u;
  TF_ROUND(17u) TF_ROUND(29u) TF_ROUND(16u) TF_ROUND(24u)
  a += ks1; b += ks2 + 4u;
  TF_ROUND(13u) TF_ROUND(15u) TF_ROUND(26u) TF_ROUND(6u)
  a += ks2; b += ks0 + 5u;
#undef TF_ROUND
  o0 = a; o1 = b;
}

// Branchless fdlibm s_log1pf for x in (-1, 0] — bit-exact port (see R12).
__device__ __forceinline__ float fdlibm_log1pf_nb(float x) {
#pragma clang fp contract(off)
  const float ln2_hi = __uint_as_float(0x3f317180u);
  const float ln2_lo = __uint_as_float(0x3717f7d1u);
  const float Lp1 = __uint_as_float(0x3F2AAAABu);
  const float Lp2 = __uint_as_float(0x3ECCCCCDu);
  const float Lp3 = __uint_as_float(0x3E924925u);
  const float Lp4 = __uint_as_float(0x3E638E29u);
  const float Lp5 = __uint_as_float(0x3E3A3325u);
  const float Lp6 = __uint_as_float(0x3E1CD04Fu);
  const float Lp7 = __uint_as_float(0x3E178897u);

  uint32_t hx = __float_as_uint(x);
  uint32_t ax = hx & 0x7fffffffu;

  // k != 0 machinery (valid everywhere; selected below)
  float u = 1.0f + x;
  uint32_t hu = __float_as_uint(u);
  int k = (int)(hu >> 23) - 127;
  float c = x - (u - 1.0f);
  c = c / u;                              // f32 IEEE div
  uint32_t m = hu & 0x007fffffu;
  bool half = (m >= 0x3504f7u);
  int k2 = half ? (k + 1) : k;
  float u2 = __uint_as_float(m | (half ? 0x3f000000u : 0x3f800000u));
  float f2 = u2 - 1.0f;

  // k == 0 region: x > -0.29289323 (fdlibm: hx <= 0xbe95f61f)
  bool cond0 = ((int32_t)hx <= (int32_t)0xbe95f61fu);
  float kf = cond0 ? 0.0f : (float)k2;
  float ff = cond0 ? x : f2;
  float cc = cond0 ? 0.0f : c;

  // shared fdlibm tail
  float hfsq = (0.5f * ff) * ff;
  float s = ff / (2.0f + ff);             // f32 IEEE div
  float z = s * s;
  float R = z * (Lp1 + z * (Lp2 + z * (Lp3 + z * (Lp4 +
            z * (Lp5 + z * (Lp6 + z * Lp7))))));
  float lowsum = s * (hfsq + R) + (kf * ln2_lo + cc);
  float res = kf * ln2_hi - ((hfsq - lowsum) - ff);

  // tiny-|x| overrides
  float tiny2 = x - (x * x) * 0.5f;
  res = (ax < 0x38000000u) ? ((ax < 0x33800000u) ? x : tiny2) : res;
  return res;
}

__global__ void __launch_bounds__(256) poisson_count_kernel(
    const float* __restrict__ rates, int* __restrict__ out) {
#pragma clang fp contract(off)
  int wid  = blockIdx.x * 4 + ((int)threadIdx.x >> 6);
  int lane = (int)threadIdx.x & 63;
  uint32_t base = (uint32_t)wid * kEPW;
  uint32_t next = 0;                       // wave-uniform: elements handed out
  uint64_t lmask_lt = (1ull << lane) - 1ull;

  // per-lane element state
  uint32_t o = 0;
  float run = 0.0f;
  int cnt = 0, s = 0;
  double inv_d = 0.0;
  bool active = false;

  while (true) {
    uint64_t needmask = __ballot(!active);
    if (needmask != 0ull) {
      uint32_t avail = kEPW - next;
      if (avail != 0u) {
        if (!active) {
          uint32_t rank = (uint32_t)__popcll(needmask & lmask_lt);
          if (rank < avail) {
            o = base + next + rank;
            float rate = rates[o];
            inv_d = 1.0 / (double)rate;    // CR f64 reciprocal (per element)
            run = 0.0f; cnt = 0; s = 0;
            active = true;
          }
        }
        uint32_t nneed = (uint32_t)__popcll(needmask);
        next += (nneed < avail) ? nneed : avail;
      } else if (needmask == ~0ull) {
        break;                             // pool empty, all lanes idle
      }
    }

    if (active) {
      uint32_t j = ((uint32_t)s << 20) + o;   // kElems == 2^20
      uint32_t b1, b2;
      threefry2x32_0_42(0u, j, b1, b2);
      uint32_t bits = b1 ^ b2;
      float uu = __uint_as_float((bits >> 9) | 0x3f800000u) - 1.0f;  // [0, 1)
      float expo = -fdlibm_log1pf_nb(-uu);
      float q = (float)((double)expo * inv_d);  // == expo / rate (IEEE f32)
      float delta = q + 0.002f;
      run = run + delta;                   // sequential f32 cumsum
      cnt += (run < 1.0f) ? 1 : 0;
      s += 1;
      if (!(run < 1.0f) || s == kSpikes) { // early exit (monotone) or cap
        out[o] = cnt;
        active = false;
      }
    }
  }
}

extern "C" void kernel_launch(void* const* d_in, const int* in_sizes, int n_in,
                              void* d_out, int out_size, void* d_ws, size_t ws_size,
                              hipStream_t stream) {
  const float* rates = (const float*)d_in[0];
  int* out = (int*)d_out;
  (void)in_sizes; (void)n_in; (void)out_size; (void)d_ws; (void)ws_size;
  poisson_count_kernel<<<kBlocks, 256, 0, stream>>>(rates, out);
}